// Round 1
// baseline (8952.451 us; speedup 1.0000x reference)
//
#include <hip/hip_runtime.h>
#include <hip/hip_bf16.h>

#define B_ 128
#define T_ 512
#define H_ 256
#define G4_ 1024   // 4*H
#define D_ 128

typedef short s8v   __attribute__((ext_vector_type(8)));   // 8 bf16 (as shorts) = MFMA A/B frag
typedef float f32x4 __attribute__((ext_vector_type(4)));
typedef unsigned short u16x4 __attribute__((ext_vector_type(4)));
typedef unsigned short u16x8 __attribute__((ext_vector_type(8)));
typedef unsigned int   u32x4 __attribute__((ext_vector_type(4)));
typedef unsigned short ush;

// ---- static device workspace (independent of ws_size) ----
__device__ __align__(256) ush   g_xw[(size_t)T_ * B_ * 2048];   // [t][b][dir*1024+gatecol] bf16 (reused by both layers)
__device__ __align__(256) ush   g_hseq[(size_t)T_ * B_ * 512];  // [t][b][dir*256+hc] bf16 (layer1 sequences)
__device__ __align__(256) ush   g_hbuf[2 * 2 * 2 * B_ * H_];    // [layer][ping][dir][b][hc] bf16
__device__ __align__(256) float g_hT[B_ * 512];                 // final layer2 states, f32
__device__ __align__(256) unsigned g_ctr[64];                   // barrier counters [layer*2+dir]

__device__ __forceinline__ ush f2b(float f) {
  unsigned u = __builtin_bit_cast(unsigned, f);
  u += 0x7FFFu + ((u >> 16) & 1u);               // RNE
  return (ush)(u >> 16);
}
__device__ __forceinline__ float b2f(ush h) {
  unsigned u = ((unsigned)h) << 16;
  return __builtin_bit_cast(float, u);
}
__device__ __forceinline__ float sigm(float x) {
  x = fminf(15.f, fmaxf(-15.f, x));
  return 1.f / (1.f + __expf(-x));
}
__device__ __forceinline__ float tanh_(float x) {
  x = fminf(8.f, fmaxf(-8.f, x));
  float e = __expf(-2.f * x);
  return (1.f - e) / (1.f + e);
}

// ============================================================
// GEMM: xw[t][b][dir*1024+col] = A[t*128+b][:] @ W[:,col]  (bf16 in, f32 acc, bf16 out)
// mode 0: A row = emb[x[b][t]]  (K=128)   mode 1: A row = g_hseq[t][b]  (K=512)
// tile: M=128 (one t), N=128, BK=64 chunks. 512 threads = 8 waves, wave = 16-row m-strip.
// ============================================================
__global__ __launch_bounds__(512, 4) void gemm_xw(
    int mode, const int* __restrict__ xi, const float* __restrict__ emb,
    const float* __restrict__ Wf, const float* __restrict__ Wb, int ktot)
{
  __shared__ __align__(16) ush A_lds[128 * 72];   // [row][k] pad->stride 144B (2-way free)
  __shared__ __align__(16) ush BT_lds[128 * 72];  // [n][k]
  const int tid = threadIdx.x;
  const int lane = tid & 63;
  const int w = tid >> 6;
  const int nb = blockIdx.x;
  const int t = blockIdx.y;
  const int dir = blockIdx.z;
  const float* Wt = dir ? Wb : Wf;

  const f32x4 zero4 = {0.f, 0.f, 0.f, 0.f};
  f32x4 acc[8];
#pragma unroll
  for (int i = 0; i < 8; ++i) acc[i] = zero4;

  const int rowA0 = tid >> 3;   // 0..63 ; second chunk handles rowA0+64
  const int ccA = tid & 7;      // 8-bf16 chunk within 64-wide K slab
  int idx0 = 0, idx1 = 0;
  if (mode == 0) {
    idx0 = xi[rowA0 * T_ + t];
    idx1 = xi[(rowA0 + 64) * T_ + t];
  }

  const int nch = ktot >> 6;
  for (int kc = 0; kc < nch; ++kc) {
    __syncthreads();   // previous chunk's MFMA reads done
    // ---- stage A [128][64] bf16 ----
    if (mode == 0) {
      {
        const float* s = emb + (size_t)idx0 * D_ + kc * 64 + ccA * 8;
        f32x4 a = *(const f32x4*)s;
        f32x4 b = *(const f32x4*)(s + 4);
        u16x8 v;
        v[0]=f2b(a[0]); v[1]=f2b(a[1]); v[2]=f2b(a[2]); v[3]=f2b(a[3]);
        v[4]=f2b(b[0]); v[5]=f2b(b[1]); v[6]=f2b(b[2]); v[7]=f2b(b[3]);
        *(u16x8*)&A_lds[rowA0 * 72 + ccA * 8] = v;
      }
      {
        const float* s = emb + (size_t)idx1 * D_ + kc * 64 + ccA * 8;
        f32x4 a = *(const f32x4*)s;
        f32x4 b = *(const f32x4*)(s + 4);
        u16x8 v;
        v[0]=f2b(a[0]); v[1]=f2b(a[1]); v[2]=f2b(a[2]); v[3]=f2b(a[3]);
        v[4]=f2b(b[0]); v[5]=f2b(b[1]); v[6]=f2b(b[2]); v[7]=f2b(b[3]);
        *(u16x8*)&A_lds[(rowA0 + 64) * 72 + ccA * 8] = v;
      }
    } else {
      {
        const ush* s = g_hseq + ((size_t)(t * B_ + rowA0)) * 512 + kc * 64 + ccA * 8;
        *(u32x4*)&A_lds[rowA0 * 72 + ccA * 8] = *(const u32x4*)s;
      }
      {
        const ush* s = g_hseq + ((size_t)(t * B_ + rowA0 + 64)) * 512 + kc * 64 + ccA * 8;
        *(u32x4*)&A_lds[(rowA0 + 64) * 72 + ccA * 8] = *(const u32x4*)s;
      }
    }
    // ---- stage B^T [128 n][64 k] bf16 (transpose during store) ----
#pragma unroll
    for (int it = 0; it < 4; ++it) {
      int cid = tid + it * 512;       // 2048 quads
      int k = cid >> 5;               // 0..63
      int n0 = (cid & 31) * 4;        // 0..124
      f32x4 wv = *(const f32x4*)(Wt + (size_t)(kc * 64 + k) * G4_ + nb * 128 + n0);
      BT_lds[(n0 + 0) * 72 + k] = f2b(wv[0]);
      BT_lds[(n0 + 1) * 72 + k] = f2b(wv[1]);
      BT_lds[(n0 + 2) * 72 + k] = f2b(wv[2]);
      BT_lds[(n0 + 3) * 72 + k] = f2b(wv[3]);
    }
    __syncthreads();
    // ---- MFMA ----
#pragma unroll
    for (int kt = 0; kt < 2; ++kt) {
      const int koff = kt * 32 + ((lane >> 4) << 3);
      s8v af = *(const s8v*)&A_lds[(w * 16 + (lane & 15)) * 72 + koff];
#pragma unroll
      for (int nt = 0; nt < 8; ++nt) {
        s8v bf = *(const s8v*)&BT_lds[(nt * 16 + (lane & 15)) * 72 + koff];
        acc[nt] = __builtin_amdgcn_mfma_f32_16x16x32_bf16(af, bf, acc[nt], 0, 0, 0);
      }
    }
  }
  // ---- store C (bf16, direct) ----
  ush* dst = g_xw + ((size_t)t * B_) * 2048 + dir * 1024 + nb * 128;
#pragma unroll
  for (int nt = 0; nt < 8; ++nt) {
#pragma unroll
    for (int jj = 0; jj < 4; ++jj) {
      int row = w * 16 + ((lane >> 4) << 2) + jj;
      int col = nt * 16 + (lane & 15);
      dst[(size_t)row * 2048 + col] = f2b(acc[nt][jj]);
    }
  }
}

// ============================================================
// Persistent LSTM recurrence. 32 WGs = 2 dirs x 16 gate-groups.
// WG (dir,g16) owns h-cols [g16*16, g16*16+16) -> 64 gate cols {g*256+hc}.
// U-slice lives as hoisted register B-fragments. Per step: all-gather h (64KB)
// into swizzled LDS, MFMA z=h@U, activations, write h-slice, 16-WG flag barrier.
// 512 threads = 8 waves = (mh in 0..1) x (ns in 0..3).
// ============================================================
__global__ __launch_bounds__(512, 2) void lstm_rec(
    int layer, const float* __restrict__ Uf, const float* __restrict__ Ub,
    const float* __restrict__ bfp, const float* __restrict__ bbp,
    int writeSeq)
{
  __shared__ __align__(16) unsigned char smem[65536];
  ush* h_lds = (ush*)smem;      // [128][256] bf16, XOR-swizzled 16B chunks
  float* zb = (float*)smem;     // [128][68] f32 (aliased; used after MFMA reads done)
  ush* U_tmp = (ush*)smem;      // [64][264] bf16 (init only, aliased)

  const int tid = threadIdx.x;
  const int lane = tid & 63;
  const int w = tid >> 6;
  const int dir = blockIdx.x >> 4;
  const int g16 = blockIdx.x & 15;
  const int hc0 = g16 * 16;
  const float* U = dir ? Ub : Uf;
  const float* bias = dir ? bbp : bfp;

  // ---- stage U-slice (transposed, bf16) into LDS ----
  for (int idx = tid; idx < 64 * 256; idx += 512) {
    int n = idx & 63, k = idx >> 6;
    int gcol = ((n >> 4) << 8) + hc0 + (n & 15);
    U_tmp[n * 264 + k] = f2b(U[(size_t)k * G4_ + gcol]);
  }
  __syncthreads();
  // ---- hoist B-fragments to registers (8 k-tiles x 4 VGPRs) ----
  const int mh = w >> 2, ns = w & 3;
  s8v bfr[8];
  {
    int n = ns * 16 + (lane & 15);
#pragma unroll
    for (int kt = 0; kt < 8; ++kt)
      bfr[kt] = *(const s8v*)&U_tmp[n * 264 + kt * 32 + ((lane >> 4) << 3)];
  }
  // ---- hoist bias for act lanes: row=w*16+(lane>>2), cols (lane&3)*4..+3 per gate ----
  float bias_r[4][4];
#pragma unroll
  for (int g = 0; g < 4; ++g)
#pragma unroll
    for (int j = 0; j < 4; ++j)
      bias_r[g][j] = bias[g * 256 + hc0 + (lane & 3) * 4 + j];
  __syncthreads();   // U_tmp reads complete before h_lds is written

  float c_[4] = {0.f, 0.f, 0.f, 0.f};
  ush* hb_base = g_hbuf + (size_t)layer * (2 * 2 * B_ * H_);
  unsigned* ctr = &g_ctr[layer * 2 + dir];
  const f32x4 zero4 = {0.f, 0.f, 0.f, 0.f};

  for (int s = 0; s < T_; ++s) {
    const int t = dir ? (T_ - 1 - s) : s;
    const int p = s & 1;
    const ush* hsrc = hb_base + (size_t)(p * 2 + dir) * B_ * H_;
    ush* hdst = hb_base + (size_t)((p ^ 1) * 2 + dir) * B_ * H_;

    // prefetch xw for the act phase (this lane's 4 gates x 4 cols)
    u16x4 xwv[4];
    {
      int row = w * 16 + (lane >> 2);
      const ush* xp = g_xw + ((size_t)(t * B_ + row)) * 2048 + dir * 1024 + hc0 + (lane & 3) * 4;
#pragma unroll
      for (int g = 0; g < 4; ++g) xwv[g] = *(const u16x4*)(xp + g * 256);
    }
    // ---- stage h(prev) -> LDS, XOR-swizzled 16B chunks ----
#pragma unroll
    for (int i = 0; i < 8; ++i) {
      int cid = i * 512 + tid;
      int row = cid >> 5, cs = cid & 31;
      int cg = cs ^ (row & 31);
      u32x4 v = *(const u32x4*)(hsrc + (size_t)row * 256 + cg * 8);
      *(u32x4*)&h_lds[row * 256 + cs * 8] = v;
    }
    __syncthreads();
    // ---- MFMA: z[128,64] = h[128,256] @ Uslice[256,64] ----
    f32x4 acc[4];
#pragma unroll
    for (int mt = 0; mt < 4; ++mt) acc[mt] = zero4;
#pragma unroll
    for (int kt = 0; kt < 8; ++kt) {
#pragma unroll
      for (int mt = 0; mt < 4; ++mt) {
        int row = mh * 64 + mt * 16 + (lane & 15);
        int kc8 = kt * 4 + (lane >> 4);
        int cs = kc8 ^ (row & 31);
        s8v af = *(const s8v*)&h_lds[row * 256 + cs * 8];
        acc[mt] = __builtin_amdgcn_mfma_f32_16x16x32_bf16(af, bfr[kt], acc[mt], 0, 0, 0);
      }
    }
    __syncthreads();   // all h_lds reads done; reuse LDS as zb
    // ---- scatter z into LDS for cross-wave gate combine ----
#pragma unroll
    for (int mt = 0; mt < 4; ++mt)
#pragma unroll
      for (int jj = 0; jj < 4; ++jj)
        zb[(mh * 64 + mt * 16 + ((lane >> 4) << 2) + jj) * 68 + ns * 16 + (lane & 15)] = acc[mt][jj];
    __syncthreads();
    // ---- activations + state update: lane owns (row = w*16+(lane>>2), 4 h-cols) ----
    {
      int row = w * 16 + (lane >> 2);
      const float* zr = zb + row * 68 + (lane & 3) * 4;
      f32x4 zi = *(const f32x4*)(zr + 0);
      f32x4 zf = *(const f32x4*)(zr + 16);
      f32x4 zg = *(const f32x4*)(zr + 32);
      f32x4 zo = *(const f32x4*)(zr + 48);
      float hv[4];
#pragma unroll
      for (int j = 0; j < 4; ++j) {
        float vi = zi[j] + b2f(xwv[0][j]) + bias_r[0][j];
        float vf = zf[j] + b2f(xwv[1][j]) + bias_r[1][j];
        float vg = zg[j] + b2f(xwv[2][j]) + bias_r[2][j];
        float vo = zo[j] + b2f(xwv[3][j]) + bias_r[3][j];
        float ig = sigm(vi), fg = sigm(vf), gg = tanh_(vg), og = sigm(vo);
        float cc = fg * c_[j] + ig * gg;
        c_[j] = cc;
        hv[j] = og * tanh_(cc);
      }
      u16x4 hp;
#pragma unroll
      for (int j = 0; j < 4; ++j) hp[j] = f2b(hv[j]);
      *(u16x4*)(hdst + (size_t)row * H_ + hc0 + (lane & 3) * 4) = hp;
      if (writeSeq) {
        *(u16x4*)(g_hseq + ((size_t)(t * B_ + row)) * 512 + dir * H_ + hc0 + (lane & 3) * 4) = hp;
      } else if (s == T_ - 1) {
        f32x4 hf;
#pragma unroll
        for (int j = 0; j < 4; ++j) hf[j] = hv[j];
        *(f32x4*)(g_hT + (size_t)row * 512 + dir * H_ + hc0 + (lane & 3) * 4) = hf;
      }
    }
    // ---- 16-WG barrier for this (layer,dir) ----
    __syncthreads();   // s_barrier drains vmcnt: all h stores are in L2
    if (tid == 0) {
      __hip_atomic_fetch_add(ctr, 1u, __ATOMIC_RELEASE, __HIP_MEMORY_SCOPE_AGENT);
      unsigned tgt = 16u * (unsigned)(s + 1);
      while (__hip_atomic_load(ctr, __ATOMIC_RELAXED, __HIP_MEMORY_SCOPE_AGENT) < tgt) {
        __builtin_amdgcn_s_sleep(2);
      }
    }
    __syncthreads();
    __builtin_amdgcn_fence(__ATOMIC_ACQUIRE, "agent");   // invalidate stale L1/L2 before next h read
  }
}

// ============================================================
// Dense [128,512]@[512,10] + bias + softmax -> out f32
// ============================================================
__global__ __launch_bounds__(512, 1) void dense_softmax(
    const float* __restrict__ Wd, const float* __restrict__ bd, float* __restrict__ out)
{
  __shared__ float wT[10 * 512];
  __shared__ float part[512 * 10];
  int tid = threadIdx.x;
  for (int i = tid; i < 5120; i += 512) {
    int k = i / 10, j = i - k * 10;
    wT[j * 512 + k] = Wd[i];
  }
  __syncthreads();
  int row = tid >> 2, q = tid & 3;
  float acc[10];
#pragma unroll
  for (int j = 0; j < 10; ++j) acc[j] = 0.f;
  const float* hrow = g_hT + (size_t)row * 512 + q * 128;
  for (int kk = 0; kk < 32; ++kk) {
    f32x4 h4 = *(const f32x4*)(hrow + kk * 4);
#pragma unroll
    for (int j = 0; j < 10; ++j) {
      f32x4 w4 = *(const f32x4*)&wT[j * 512 + q * 128 + kk * 4];
      acc[j] += h4[0] * w4[0] + h4[1] * w4[1] + h4[2] * w4[2] + h4[3] * w4[3];
    }
  }
#pragma unroll
  for (int j = 0; j < 10; ++j) part[tid * 10 + j] = acc[j];
  __syncthreads();
  if (tid < 128) {
    float lg[10];
#pragma unroll
    for (int j = 0; j < 10; ++j)
      lg[j] = bd[j] + part[(tid * 4 + 0) * 10 + j] + part[(tid * 4 + 1) * 10 + j]
                    + part[(tid * 4 + 2) * 10 + j] + part[(tid * 4 + 3) * 10 + j];
    float m = lg[0];
#pragma unroll
    for (int j = 1; j < 10; ++j) m = fmaxf(m, lg[j]);
    float ssum = 0.f;
#pragma unroll
    for (int j = 0; j < 10; ++j) { lg[j] = __expf(lg[j] - m); ssum += lg[j]; }
    float inv = 1.f / ssum;
#pragma unroll
    for (int j = 0; j < 10; ++j) out[tid * 10 + j] = lg[j] * inv;
  }
}

extern "C" void kernel_launch(void* const* d_in, const int* in_sizes, int n_in,
                              void* d_out, int out_size, void* d_ws, size_t ws_size,
                              hipStream_t stream) {
  (void)in_sizes; (void)n_in; (void)d_ws; (void)ws_size; (void)out_size;
  const int* x = (const int*)d_in[0];
  const float* emb = (const float*)d_in[1];
  const float* W1f = (const float*)d_in[2];
  const float* U1f = (const float*)d_in[3];
  const float* b1f = (const float*)d_in[4];
  const float* W1b = (const float*)d_in[5];
  const float* U1b = (const float*)d_in[6];
  const float* b1b = (const float*)d_in[7];
  const float* W2f = (const float*)d_in[8];
  const float* U2f = (const float*)d_in[9];
  const float* b2f = (const float*)d_in[10];
  const float* W2b = (const float*)d_in[11];
  const float* U2b = (const float*)d_in[12];
  const float* b2b = (const float*)d_in[13];
  const float* Wd  = (const float*)d_in[14];
  const float* bd  = (const float*)d_in[15];
  float* out = (float*)d_out;

  void* ctr_p = nullptr; void* hbuf_p = nullptr;
  hipGetSymbolAddress(&ctr_p, HIP_SYMBOL(g_ctr));
  hipGetSymbolAddress(&hbuf_p, HIP_SYMBOL(g_hbuf));
  hipMemsetAsync(ctr_p, 0, 64 * sizeof(unsigned), stream);
  hipMemsetAsync(hbuf_p, 0, (size_t)2 * 2 * 2 * B_ * H_ * sizeof(ush), stream);

  // layer 1 input projection: e = emb[x] (bf16) @ W1{f,b}
  gemm_xw<<<dim3(8, T_, 2), 512, 0, stream>>>(0, x, emb, W1f, W1b, 128);
  // layer 1 recurrence (writes hseq)
  lstm_rec<<<32, 512, 0, stream>>>(0, U1f, U1b, b1f, b1b, 1);
  // layer 2 input projection: seq @ W2{f,b}
  gemm_xw<<<dim3(8, T_, 2), 512, 0, stream>>>(1, nullptr, nullptr, W2f, W2b, 512);
  // layer 2 recurrence (writes hT f32 at last step)
  lstm_rec<<<32, 512, 0, stream>>>(1, U2f, U2b, b2f, b2b, 0);
  // dense + softmax
  dense_softmax<<<1, 512, 0, stream>>>(Wd, bd, out);
}

// Round 2
// 4652.040 us; speedup vs baseline: 1.9244x; 1.9244x over previous
//
#include <hip/hip_runtime.h>
#include <hip/hip_bf16.h>

#define B_ 128
#define T_ 512
#define H_ 256
#define G4_ 1024   // 4*H
#define D_ 128

typedef short s8v   __attribute__((ext_vector_type(8)));   // 8 bf16 (as shorts) = MFMA A/B frag
typedef float f32x4 __attribute__((ext_vector_type(4)));
typedef unsigned short u16x4 __attribute__((ext_vector_type(4)));
typedef unsigned short u16x8 __attribute__((ext_vector_type(8)));
typedef unsigned int   u32x4 __attribute__((ext_vector_type(4)));
typedef unsigned short ush;
typedef unsigned long long ull;

// ---- static device workspace ----
// xw permuted: [t][dir][b][hc*4+g]  (4 gates contiguous per h-col)
__device__ __align__(256) ush   g_xw[(size_t)T_ * 2 * B_ * G4_];
__device__ __align__(256) ush   g_hseq[(size_t)T_ * B_ * 512];  // [t][b][dir*256+hc] bf16
// exchange buffer, col-major tiles: [slice][dir][ping][col 0..255][row 0..15] bf16
__device__ __align__(256) ush   g_hx[8 * 2 * 2 * 256 * 16];
__device__ __align__(256) float g_hT[B_ * 512];                 // final layer2 states, f32
// subflags: [layer][slice][dir][nh][wave*8]  (32B spacing per wave flag)
__device__ __align__(256) unsigned g_flags[2 * 8 * 2 * 2 * 64];

__device__ __forceinline__ ush f2b(float f) {
  unsigned u = __builtin_bit_cast(unsigned, f);
  u += 0x7FFFu + ((u >> 16) & 1u);               // RNE
  return (ush)(u >> 16);
}
__device__ __forceinline__ float b2f(ush h) {
  unsigned u = ((unsigned)h) << 16;
  return __builtin_bit_cast(float, u);
}
__device__ __forceinline__ float sigm(float x) {
  x = fminf(15.f, fmaxf(-15.f, x));
  return 1.f / (1.f + __expf(-x));
}
__device__ __forceinline__ float tanh_(float x) {
  x = fminf(8.f, fmaxf(-8.f, x));
  float e = __expf(-2.f * x);
  return (1.f - e) / (1.f + e);
}

// ============================================================
// GEMM: xw_p[t][dir][b][hc*4+g] = A[t*128+b][:] @ W[:,gate*256+hc]
// mode 0: A row = emb[x[b][t]]  (K=128)   mode 1: A row = g_hseq[t][b]  (K=512)
// ============================================================
__global__ __launch_bounds__(512, 4) void gemm_xw(
    int mode, const int* __restrict__ xi, const float* __restrict__ emb,
    const float* __restrict__ Wf, const float* __restrict__ Wb, int ktot)
{
  __shared__ __align__(16) ush A_lds[128 * 72];   // [row][k] pad
  __shared__ __align__(16) ush BT_lds[128 * 72];  // [n][k]
  const int tid = threadIdx.x;
  const int lane = tid & 63;
  const int w = tid >> 6;
  const int nb = blockIdx.x;
  const int t = blockIdx.y;
  const int dir = blockIdx.z;
  const float* Wt = dir ? Wb : Wf;

  const f32x4 zero4 = {0.f, 0.f, 0.f, 0.f};
  f32x4 acc[8];
#pragma unroll
  for (int i = 0; i < 8; ++i) acc[i] = zero4;

  const int rowA0 = tid >> 3;
  const int ccA = tid & 7;
  int idx0 = 0, idx1 = 0;
  if (mode == 0) {
    idx0 = xi[rowA0 * T_ + t];
    idx1 = xi[(rowA0 + 64) * T_ + t];
  }

  const int nch = ktot >> 6;
  for (int kc = 0; kc < nch; ++kc) {
    __syncthreads();
    if (mode == 0) {
      {
        const float* s = emb + (size_t)idx0 * D_ + kc * 64 + ccA * 8;
        f32x4 a = *(const f32x4*)s;
        f32x4 b = *(const f32x4*)(s + 4);
        u16x8 v;
        v[0]=f2b(a[0]); v[1]=f2b(a[1]); v[2]=f2b(a[2]); v[3]=f2b(a[3]);
        v[4]=f2b(b[0]); v[5]=f2b(b[1]); v[6]=f2b(b[2]); v[7]=f2b(b[3]);
        *(u16x8*)&A_lds[rowA0 * 72 + ccA * 8] = v;
      }
      {
        const float* s = emb + (size_t)idx1 * D_ + kc * 64 + ccA * 8;
        f32x4 a = *(const f32x4*)s;
        f32x4 b = *(const f32x4*)(s + 4);
        u16x8 v;
        v[0]=f2b(a[0]); v[1]=f2b(a[1]); v[2]=f2b(a[2]); v[3]=f2b(a[3]);
        v[4]=f2b(b[0]); v[5]=f2b(b[1]); v[6]=f2b(b[2]); v[7]=f2b(b[3]);
        *(u16x8*)&A_lds[(rowA0 + 64) * 72 + ccA * 8] = v;
      }
    } else {
      {
        const ush* s = g_hseq + ((size_t)(t * B_ + rowA0)) * 512 + kc * 64 + ccA * 8;
        *(u32x4*)&A_lds[rowA0 * 72 + ccA * 8] = *(const u32x4*)s;
      }
      {
        const ush* s = g_hseq + ((size_t)(t * B_ + rowA0 + 64)) * 512 + kc * 64 + ccA * 8;
        *(u32x4*)&A_lds[(rowA0 + 64) * 72 + ccA * 8] = *(const u32x4*)s;
      }
    }
#pragma unroll
    for (int it = 0; it < 4; ++it) {
      int cid = tid + it * 512;
      int k = cid >> 5;
      int n0 = (cid & 31) * 4;
      f32x4 wv = *(const f32x4*)(Wt + (size_t)(kc * 64 + k) * G4_ + nb * 128 + n0);
      BT_lds[(n0 + 0) * 72 + k] = f2b(wv[0]);
      BT_lds[(n0 + 1) * 72 + k] = f2b(wv[1]);
      BT_lds[(n0 + 2) * 72 + k] = f2b(wv[2]);
      BT_lds[(n0 + 3) * 72 + k] = f2b(wv[3]);
    }
    __syncthreads();
#pragma unroll
    for (int kt = 0; kt < 2; ++kt) {
      const int koff = kt * 32 + ((lane >> 4) << 3);
      s8v af = *(const s8v*)&A_lds[(w * 16 + (lane & 15)) * 72 + koff];
#pragma unroll
      for (int nt = 0; nt < 8; ++nt) {
        s8v bf = *(const s8v*)&BT_lds[(nt * 16 + (lane & 15)) * 72 + koff];
        acc[nt] = __builtin_amdgcn_mfma_f32_16x16x32_bf16(af, bf, acc[nt], 0, 0, 0);
      }
    }
  }
  // store to permuted layout [t][dir][row][hc*4+g]
  ush* dst = g_xw + ((size_t)t * 2 + dir) * ((size_t)B_ * G4_);
#pragma unroll
  for (int nt = 0; nt < 8; ++nt) {
    int colg = nb * 128 + nt * 16 + (lane & 15);   // global gate col 0..1023
    int g = colg >> 8, hc = colg & 255;
#pragma unroll
    for (int jj = 0; jj < 4; ++jj) {
      int row = w * 16 + ((lane >> 4) << 2) + jj;
      dst[(size_t)row * 1024 + hc * 4 + g] = f2b(acc[nt][jj]);
    }
  }
}

// ============================================================
// Persistent LSTM recurrence, batch-split + column-pair design.
// 32 WGs: dir = bx>>4, nh = (bx>>3)&1, slice = bx&7  (pair = bx^8, same XCD heuristic).
// WG: M=16 batch rows (slice), gate cols {g*256 + nh*128 + w*16 + [0,16)} per wave.
// U-half hoisted in registers (128 VGPR/wave). Pair exchanges h[16,128]=4KB/step via
// L3-coherent (SYSTEM-scope) b64 ops + per-wave monotonic flags. No fences, no L2 inv.
// ============================================================
__global__ __launch_bounds__(512, 2) void lstm_rec(
    int layer, const float* __restrict__ Uf, const float* __restrict__ Ub,
    const float* __restrict__ bfp, const float* __restrict__ bbp,
    int writeSeq)
{
  __shared__ __align__(16) ush h_lds[2][16 * 256];   // ping-pong, XOR-swizzled 16B chunks

  const int tid = threadIdx.x;
  const int lane = tid & 63;
  const int w = tid >> 6;
  const int dir = blockIdx.x >> 4;
  const int nh = (blockIdx.x >> 3) & 1;
  const int slice = blockIdx.x & 7;
  const float* U = dir ? Ub : Uf;
  const float* bias = dir ? bbp : bfp;

  const int l15 = lane & 15;
  const int lq = lane >> 4;        // 0..3
  const int mycol = nh * 128 + w * 16 + l15;   // h-col this lane produces
  const int rowb = slice * 16;

  // ---- hoist U-half B-fragments: bfr[gate][ktile], 128 VGPRs ----
  s8v bfr[4][8];
#pragma unroll
  for (int g = 0; g < 4; ++g) {
    int colb = g * 256 + mycol;
#pragma unroll
    for (int kt = 0; kt < 8; ++kt) {
      s8v v;
#pragma unroll
      for (int j = 0; j < 8; ++j) {
        int k = kt * 32 + lq * 8 + j;
        v[j] = (short)f2b(U[(size_t)k * G4_ + colb]);
      }
      bfr[g][kt] = v;
    }
  }
  float bias_r[4];
#pragma unroll
  for (int g = 0; g < 4; ++g) bias_r[g] = bias[g * 256 + mycol];

  // ---- zero both LDS h buffers (h_0 = 0) ----
  {
    ull* z = (ull*)&h_lds[0][0];
    for (int i = tid; i < 2048; i += 512) z[i] = 0ull;
  }
  __syncthreads();

  float c_[4] = {0.f, 0.f, 0.f, 0.f};

  const int fb_own = (((layer * 8 + slice) * 2 + dir) * 2 + nh) * 64;
  const int fb_par = (((layer * 8 + slice) * 2 + dir) * 2 + (nh ^ 1)) * 64;
  ush* hx_base = g_hx + (((size_t)slice * 2 + dir) * 2) * (256 * 16);

  for (int s = 0; s < T_; ++s) {
    const int t = dir ? (T_ - 1 - s) : s;
    const int p = s & 1;

    // ---- prefetch xw (4 rows x 4 gates, contiguous per row) ----
    u16x4 xv[4];
    {
      const ush* xp = g_xw + (((size_t)t * 2 + dir) * B_ + rowb) * 1024 + mycol * 4;
#pragma unroll
      for (int j = 0; j < 4; ++j)
        xv[j] = *(const u16x4*)(xp + (size_t)(lq * 4 + j) * 1024);
    }
    // ---- A-fragments from LDS buf[p] (swizzled) ----
    s8v af[8];
    {
      int row = l15;
#pragma unroll
      for (int kt = 0; kt < 8; ++kt) {
        int c8 = kt * 4 + lq;
        af[kt] = *(const s8v*)&h_lds[p][row * 256 + ((c8 ^ row) & 31) * 8];
      }
    }
    // ---- MFMA: z[16, 64cols] per wave (4 gate-tiles, same 16 h-cols) ----
    f32x4 acc[4];
    const f32x4 zero4 = {0.f, 0.f, 0.f, 0.f};
#pragma unroll
    for (int g = 0; g < 4; ++g) acc[g] = zero4;
#pragma unroll
    for (int kt = 0; kt < 8; ++kt) {
#pragma unroll
      for (int g = 0; g < 4; ++g)
        acc[g] = __builtin_amdgcn_mfma_f32_16x16x32_bf16(af[kt], bfr[g][kt], acc[g], 0, 0, 0);
    }
    // ---- activations, in-lane (rows lq*4+j, col mycol) ----
    float hf[4];
    ush hv[4];
#pragma unroll
    for (int j = 0; j < 4; ++j) {
      float vi = acc[0][j] + b2f(xv[j][0]) + bias_r[0];
      float vf = acc[1][j] + b2f(xv[j][1]) + bias_r[1];
      float vg = acc[2][j] + b2f(xv[j][2]) + bias_r[2];
      float vo = acc[3][j] + b2f(xv[j][3]) + bias_r[3];
      float ig = sigm(vi), fg = sigm(vf), gg = tanh_(vg), og = sigm(vo);
      float cc = fg * c_[j] + ig * gg;
      c_[j] = cc;
      hf[j] = og * tanh_(cc);
      hv[j] = f2b(hf[j]);
    }
    // ---- own h -> LDS buf[p^1] (swizzled scalar writes) ----
    {
      int c8o = mycol >> 3, wo = mycol & 7;
#pragma unroll
      for (int j = 0; j < 4; ++j) {
        int row = lq * 4 + j;
        h_lds[p ^ 1][row * 256 + (((c8o ^ row) & 31) * 8 + wo)] = hv[j];
      }
    }
    // ---- export own tile to exchange buffer (col-major, 1 b64/lane, L3-coherent) ----
    {
      ull ev = (ull)hv[0] | ((ull)hv[1] << 16) | ((ull)hv[2] << 32) | ((ull)hv[3] << 48);
      ush* hxp = hx_base + ((size_t)(p ^ 1) * 256 + mycol) * 16 + lq * 4;
      __hip_atomic_store((ull*)hxp, ev, __ATOMIC_RELAXED, __HIP_MEMORY_SCOPE_SYSTEM);
    }
    // ---- sequence / final-state outputs ----
    if (writeSeq) {
#pragma unroll
      for (int j = 0; j < 4; ++j)
        g_hseq[((size_t)t * B_ + rowb + lq * 4 + j) * 512 + dir * 256 + mycol] = hv[j];
    } else if (s == T_ - 1) {
#pragma unroll
      for (int j = 0; j < 4; ++j)
        g_hT[(size_t)(rowb + lq * 4 + j) * 512 + dir * 256 + mycol] = hf[j];
    }
    // ---- per-wave flag after our stores reached L3 ----
    asm volatile("s_waitcnt vmcnt(0)" ::: "memory");
    if (lane == 0)
      __hip_atomic_store(&g_flags[fb_own + w * 8], (unsigned)(s + 1),
                         __ATOMIC_RELAXED, __HIP_MEMORY_SCOPE_SYSTEM);
    // ---- poll all 8 partner wave-flags ----
    {
      bool ok;
      do {
        unsigned v = 0xFFFFFFFFu;
        if (lane < 8)
          v = __hip_atomic_load(&g_flags[fb_par + lane * 8],
                                __ATOMIC_RELAXED, __HIP_MEMORY_SCOPE_SYSTEM);
        ok = __all((int)(v >= (unsigned)(s + 1)));
        if (!ok) __builtin_amdgcn_s_sleep(1);
      } while (!ok);
    }
    asm volatile("" ::: "memory");
    // ---- load partner half (1 b64/thread) -> LDS buf[p^1] ----
    {
      int colp = (nh ^ 1) * 128 + (tid >> 2);
      int q = tid & 3;
      const ush* pp = hx_base + ((size_t)(p ^ 1) * 256 + colp) * 16 + q * 4;
      ull pv = __hip_atomic_load((const ull*)pp, __ATOMIC_RELAXED, __HIP_MEMORY_SCOPE_SYSTEM);
      int c8p = colp >> 3, wp = colp & 7;
#pragma unroll
      for (int j = 0; j < 4; ++j) {
        int row = q * 4 + j;
        h_lds[p ^ 1][row * 256 + (((c8p ^ row) & 31) * 8 + wp)] = (ush)(pv >> (16 * j));
      }
    }
    __syncthreads();
  }
}

// ============================================================
// Dense [128,512]@[512,10] + bias + softmax -> out f32
// ============================================================
__global__ __launch_bounds__(512, 1) void dense_softmax(
    const float* __restrict__ Wd, const float* __restrict__ bd, float* __restrict__ out)
{
  __shared__ float wT[10 * 512];
  __shared__ float part[512 * 10];
  int tid = threadIdx.x;
  for (int i = tid; i < 5120; i += 512) {
    int k = i / 10, j = i - k * 10;
    wT[j * 512 + k] = Wd[i];
  }
  __syncthreads();
  int row = tid >> 2, q = tid & 3;
  float acc[10];
#pragma unroll
  for (int j = 0; j < 10; ++j) acc[j] = 0.f;
  const float* hrow = g_hT + (size_t)row * 512 + q * 128;
  for (int kk = 0; kk < 32; ++kk) {
    f32x4 h4 = *(const f32x4*)(hrow + kk * 4);
#pragma unroll
    for (int j = 0; j < 10; ++j) {
      f32x4 w4 = *(const f32x4*)&wT[j * 512 + q * 128 + kk * 4];
      acc[j] += h4[0] * w4[0] + h4[1] * w4[1] + h4[2] * w4[2] + h4[3] * w4[3];
    }
  }
#pragma unroll
  for (int j = 0; j < 10; ++j) part[tid * 10 + j] = acc[j];
  __syncthreads();
  if (tid < 128) {
    float lg[10];
#pragma unroll
    for (int j = 0; j < 10; ++j)
      lg[j] = bd[j] + part[(tid * 4 + 0) * 10 + j] + part[(tid * 4 + 1) * 10 + j]
                    + part[(tid * 4 + 2) * 10 + j] + part[(tid * 4 + 3) * 10 + j];
    float m = lg[0];
#pragma unroll
    for (int j = 1; j < 10; ++j) m = fmaxf(m, lg[j]);
    float ssum = 0.f;
#pragma unroll
    for (int j = 0; j < 10; ++j) { lg[j] = __expf(lg[j] - m); ssum += lg[j]; }
    float inv = 1.f / ssum;
#pragma unroll
    for (int j = 0; j < 10; ++j) out[tid * 10 + j] = lg[j] * inv;
  }
}

extern "C" void kernel_launch(void* const* d_in, const int* in_sizes, int n_in,
                              void* d_out, int out_size, void* d_ws, size_t ws_size,
                              hipStream_t stream) {
  (void)in_sizes; (void)n_in; (void)d_ws; (void)ws_size; (void)out_size;
  const int* x = (const int*)d_in[0];
  const float* emb = (const float*)d_in[1];
  const float* W1f = (const float*)d_in[2];
  const float* U1f = (const float*)d_in[3];
  const float* b1f = (const float*)d_in[4];
  const float* W1b = (const float*)d_in[5];
  const float* U1b = (const float*)d_in[6];
  const float* b1b = (const float*)d_in[7];
  const float* W2f = (const float*)d_in[8];
  const float* U2f = (const float*)d_in[9];
  const float* b2f = (const float*)d_in[10];
  const float* W2b = (const float*)d_in[11];
  const float* U2b = (const float*)d_in[12];
  const float* b2b = (const float*)d_in[13];
  const float* Wd  = (const float*)d_in[14];
  const float* bd  = (const float*)d_in[15];
  float* out = (float*)d_out;

  void* flags_p = nullptr;
  hipGetSymbolAddress(&flags_p, HIP_SYMBOL(g_flags));
  hipMemsetAsync(flags_p, 0, sizeof(unsigned) * 2 * 8 * 2 * 2 * 64, stream);

  // layer 1 input projection: e = emb[x] (bf16) @ W1{f,b}
  gemm_xw<<<dim3(8, T_, 2), 512, 0, stream>>>(0, x, emb, W1f, W1b, 128);
  // layer 1 recurrence (writes hseq)
  lstm_rec<<<32, 512, 0, stream>>>(0, U1f, U1b, b1f, b1b, 1);
  // layer 2 input projection: seq @ W2{f,b}
  gemm_xw<<<dim3(8, T_, 2), 512, 0, stream>>>(1, nullptr, nullptr, W2f, W2b, 512);
  // layer 2 recurrence (writes hT f32 at last step)
  lstm_rec<<<32, 512, 0, stream>>>(1, U2f, U2b, b2f, b2b, 0);
  // dense + softmax
  dense_softmax<<<1, 512, 0, stream>>>(Wd, bd, out);
}

// Round 3
// 3871.657 us; speedup vs baseline: 2.3123x; 1.2016x over previous
//
#include <hip/hip_runtime.h>
#include <hip/hip_bf16.h>

#define B_ 128
#define T_ 512
#define H_ 256
#define G4_ 1024   // 4*H
#define D_ 128

typedef short s8v   __attribute__((ext_vector_type(8)));   // 8 bf16 (as shorts) = MFMA A/B frag
typedef float f32x4 __attribute__((ext_vector_type(4)));
typedef unsigned short u16x4 __attribute__((ext_vector_type(4)));
typedef unsigned short u16x8 __attribute__((ext_vector_type(8)));
typedef unsigned int   u32x4 __attribute__((ext_vector_type(4)));
typedef unsigned short ush;
typedef unsigned long long ull;

// ---- static device workspace ----
// xw permuted: [t][dir][b][hc*4+g]  (4 gates contiguous per h-col)
__device__ __align__(256) ush   g_xw[(size_t)T_ * 2 * B_ * G4_];
__device__ __align__(256) ush   g_hseq[(size_t)T_ * B_ * 512];  // [t][b][dir*256+hc] bf16
// exchange: [slice][dir][ping][col 0..255][rowpair 0..7] b64 = {bf16 lo, bf16 hi, u32 seq}
__device__ __align__(256) ull   g_hx2[8 * 2 * 2 * 256 * 8];
__device__ __align__(256) float g_hT[B_ * 512];                 // final layer2 states, f32
// pre-converted transposed bf16 weights: W1(2x131072) U1(2x262144) W2(2x524288) U2(2x262144)
__device__ __align__(256) ush   g_wtall[2359296];

__device__ __forceinline__ ush f2b(float f) {
  unsigned u = __builtin_bit_cast(unsigned, f);
  u += 0x7FFFu + ((u >> 16) & 1u);               // RNE
  return (ush)(u >> 16);
}
__device__ __forceinline__ float b2f(ush h) {
  unsigned u = ((unsigned)h) << 16;
  return __builtin_bit_cast(float, u);
}
__device__ __forceinline__ float sigm(float x) {
  x = fminf(15.f, fmaxf(-15.f, x));
  return 1.f / (1.f + __expf(-x));
}
__device__ __forceinline__ float tanh_(float x) {
  x = fminf(8.f, fmaxf(-8.f, x));
  float e = __expf(-2.f * x);
  return (1.f - e) / (1.f + e);
}

// ============================================================
// prep_w: W[k][n=1024] f32  ->  WT[n][k] bf16, 64x64 LDS tile transpose.
// grid.x = (K/64)*16, grid.z = 0(f)/1(b). 256 threads.
// ============================================================
__global__ __launch_bounds__(256, 4) void prep_w(
    const float* __restrict__ Wf, const float* __restrict__ Wb,
    ush* __restrict__ WTf, ush* __restrict__ WTb, int K)
{
  __shared__ ush tile[64][65];
  const float* W = blockIdx.z ? Wb : Wf;
  ush* WT = blockIdx.z ? WTb : WTf;
  int nt = blockIdx.x & 15, kt = blockIdx.x >> 4;
  int tid = threadIdx.x;
  for (int i = tid; i < 4096; i += 256) {
    int k = i >> 6, n = i & 63;
    tile[k][n] = f2b(W[(size_t)(kt * 64 + k) * 1024 + nt * 64 + n]);
  }
  __syncthreads();
  for (int i = tid; i < 4096; i += 256) {
    int n = i >> 6, k = i & 63;
    WT[(size_t)(nt * 64 + n) * K + kt * 64 + k] = tile[k][n];
  }
}

// ============================================================
// GEMM: xw_p[t][dir][b][hc*4+g] = A[t*128+b][:] @ W[:,gate*256+hc]
// mode 0: A row = emb[x[b][t]] (K=128)  mode 1: A row = g_hseq[t][b] (K=512)
// B operand from pre-transposed bf16 WT[n][k].
// ============================================================
__global__ __launch_bounds__(512, 4) void gemm_xw(
    int mode, const int* __restrict__ xi, const float* __restrict__ emb,
    const ush* __restrict__ WTf, const ush* __restrict__ WTb, int ktot)
{
  __shared__ __align__(16) ush A_lds[128 * 72];   // [row][k] pad
  __shared__ __align__(16) ush BT_lds[128 * 72];  // [n][k]
  const int tid = threadIdx.x;
  const int lane = tid & 63;
  const int w = tid >> 6;
  const int nb = blockIdx.x;
  const int t = blockIdx.y;
  const int dir = blockIdx.z;
  const ush* WT = dir ? WTb : WTf;

  const f32x4 zero4 = {0.f, 0.f, 0.f, 0.f};
  f32x4 acc[8];
#pragma unroll
  for (int i = 0; i < 8; ++i) acc[i] = zero4;

  const int rowA0 = tid >> 3;
  const int ccA = tid & 7;
  int idx0 = 0, idx1 = 0;
  if (mode == 0) {
    idx0 = xi[rowA0 * T_ + t];
    idx1 = xi[(rowA0 + 64) * T_ + t];
  }

  const int nch = ktot >> 6;
  for (int kc = 0; kc < nch; ++kc) {
    __syncthreads();
    // ---- stage A ----
    if (mode == 0) {
      {
        const float* s = emb + (size_t)idx0 * D_ + kc * 64 + ccA * 8;
        f32x4 a = *(const f32x4*)s;
        f32x4 b = *(const f32x4*)(s + 4);
        u16x8 v;
        v[0]=f2b(a[0]); v[1]=f2b(a[1]); v[2]=f2b(a[2]); v[3]=f2b(a[3]);
        v[4]=f2b(b[0]); v[5]=f2b(b[1]); v[6]=f2b(b[2]); v[7]=f2b(b[3]);
        *(u16x8*)&A_lds[rowA0 * 72 + ccA * 8] = v;
      }
      {
        const float* s = emb + (size_t)idx1 * D_ + kc * 64 + ccA * 8;
        f32x4 a = *(const f32x4*)s;
        f32x4 b = *(const f32x4*)(s + 4);
        u16x8 v;
        v[0]=f2b(a[0]); v[1]=f2b(a[1]); v[2]=f2b(a[2]); v[3]=f2b(a[3]);
        v[4]=f2b(b[0]); v[5]=f2b(b[1]); v[6]=f2b(b[2]); v[7]=f2b(b[3]);
        *(u16x8*)&A_lds[(rowA0 + 64) * 72 + ccA * 8] = v;
      }
    } else {
      {
        const ush* s = g_hseq + ((size_t)(t * B_ + rowA0)) * 512 + kc * 64 + ccA * 8;
        *(u32x4*)&A_lds[rowA0 * 72 + ccA * 8] = *(const u32x4*)s;
      }
      {
        const ush* s = g_hseq + ((size_t)(t * B_ + rowA0 + 64)) * 512 + kc * 64 + ccA * 8;
        *(u32x4*)&A_lds[(rowA0 + 64) * 72 + ccA * 8] = *(const u32x4*)s;
      }
    }
    // ---- stage B (bf16, pre-transposed: straight vector copy) ----
    {
      int n = tid >> 2, k8 = (tid & 3) * 2;
      const ush* src = WT + (size_t)(nb * 128 + n) * ktot + kc * 64 + k8 * 8;
      *(u32x4*)&BT_lds[n * 72 + k8 * 8] = *(const u32x4*)src;
      *(u32x4*)&BT_lds[n * 72 + k8 * 8 + 8] = *(const u32x4*)(src + 8);
    }
    __syncthreads();
#pragma unroll
    for (int kt = 0; kt < 2; ++kt) {
      const int koff = kt * 32 + ((lane >> 4) << 3);
      s8v af = *(const s8v*)&A_lds[(w * 16 + (lane & 15)) * 72 + koff];
#pragma unroll
      for (int nt = 0; nt < 8; ++nt) {
        s8v bf = *(const s8v*)&BT_lds[(nt * 16 + (lane & 15)) * 72 + koff];
        acc[nt] = __builtin_amdgcn_mfma_f32_16x16x32_bf16(af, bf, acc[nt], 0, 0, 0);
      }
    }
  }
  // store to permuted layout [t][dir][row][hc*4+g]
  ush* dst = g_xw + ((size_t)t * 2 + dir) * ((size_t)B_ * G4_);
#pragma unroll
  for (int nt = 0; nt < 8; ++nt) {
    int colg = nb * 128 + nt * 16 + (lane & 15);
    int g = colg >> 8, hc = colg & 255;
#pragma unroll
    for (int jj = 0; jj < 4; ++jj) {
      int row = w * 16 + ((lane >> 4) << 2) + jj;
      dst[(size_t)row * 1024 + hc * 4 + g] = f2b(acc[nt][jj]);
    }
  }
}

// ============================================================
// Persistent LSTM recurrence, batch-split + column-pair, fused seq-in-data exchange.
// 32 WGs: dir=bx>>4, nh=(bx>>3)&1, slice=bx&7. Pair = (slice,dir,nh^1).
// Per lane exchange granule: b64 = {h lo bf16, h hi bf16, u32 seq}; relaxed SYSTEM
// atomics; no flags, no fences, no pre-flag drains. Seq = layer*T + s + 1 (monotonic).
// ============================================================
__global__ __launch_bounds__(512, 2) void lstm_rec(
    int layer, const ush* __restrict__ UTf, const ush* __restrict__ UTb,
    const float* __restrict__ bfp, const float* __restrict__ bbp,
    int writeSeq)
{
  __shared__ __align__(16) ush h_lds[2][16 * 256];   // ping-pong, XOR-swizzled 16B chunks

  const int tid = threadIdx.x;
  const int lane = tid & 63;
  const int w = tid >> 6;
  const int dir = blockIdx.x >> 4;
  const int nh = (blockIdx.x >> 3) & 1;
  const int slice = blockIdx.x & 7;
  const ush* UT = dir ? UTb : UTf;      // [1024 col][256 k] bf16
  const float* bias = dir ? bbp : bfp;

  const int l15 = lane & 15;
  const int lq = lane >> 4;             // 0..3
  const int mycol = nh * 128 + w * 16 + l15;
  const int rowb = slice * 16;
  const unsigned sbase = (unsigned)(layer * T_);

  // ---- hoist U-half B-fragments from pre-transposed bf16 (32 wide loads) ----
  s8v bfr[4][8];
#pragma unroll
  for (int g = 0; g < 4; ++g) {
    const ush* up = UT + (size_t)(g * 256 + mycol) * 256;
#pragma unroll
    for (int kt = 0; kt < 8; ++kt)
      bfr[g][kt] = *(const s8v*)(up + kt * 32 + lq * 8);
  }
  float bias_r[4];
#pragma unroll
  for (int g = 0; g < 4; ++g) bias_r[g] = bias[g * 256 + mycol];

  // ---- zero LDS buf[0] (h_0 = 0) ----
  {
    ull* z = (ull*)&h_lds[0][0];
    for (int i = tid; i < 1024; i += 512) z[i] = 0ull;
  }
  __syncthreads();

  float c_[4] = {0.f, 0.f, 0.f, 0.f};
  ull* hxp = g_hx2 + ((size_t)(slice * 2 + dir) * 2) * (256 * 8);

  // consumer-side constants
  const int colp = (nh ^ 1) * 128 + (tid >> 2);   // partner col this thread imports
  const int q = tid & 3;                           // row-quad
  const int c8p = colp >> 3, wp = colp & 7;

  // ---- prefetch xw for s=0 ----
  u16x4 xv[4];
  {
    int t0 = dir ? (T_ - 1) : 0;
    const ush* xp = g_xw + (((size_t)t0 * 2 + dir) * B_ + rowb) * 1024 + mycol * 4;
#pragma unroll
    for (int j = 0; j < 4; ++j)
      xv[j] = *(const u16x4*)(xp + (size_t)(lq * 4 + j) * 1024);
  }

  for (int s = 0; s < T_; ++s) {
    const int p = s & 1;

    // ---- import partner half for h_s (skip s=0: zeros already in buf[0]) ----
    if (s > 0) {
      const ull* a0 = hxp + ((size_t)p * 256 + colp) * 8 + q * 2;
      unsigned target = sbase + (unsigned)s;
      ull v0, v1;
      for (;;) {
        v0 = __hip_atomic_load(a0, __ATOMIC_RELAXED, __HIP_MEMORY_SCOPE_SYSTEM);
        v1 = __hip_atomic_load(a0 + 1, __ATOMIC_RELAXED, __HIP_MEMORY_SCOPE_SYSTEM);
        if ((unsigned)(v0 >> 32) >= target && (unsigned)(v1 >> 32) >= target) break;
        __builtin_amdgcn_s_sleep(1);
      }
      ush* dstl = &h_lds[p][0];
      dstl[(q * 4 + 0) * 256 + (((c8p ^ (q * 4 + 0)) & 31) * 8 + wp)] = (ush)v0;
      dstl[(q * 4 + 1) * 256 + (((c8p ^ (q * 4 + 1)) & 31) * 8 + wp)] = (ush)(v0 >> 16);
      dstl[(q * 4 + 2) * 256 + (((c8p ^ (q * 4 + 2)) & 31) * 8 + wp)] = (ush)v1;
      dstl[(q * 4 + 3) * 256 + (((c8p ^ (q * 4 + 3)) & 31) * 8 + wp)] = (ush)(v1 >> 16);
    }
    __syncthreads();

    // ---- coalesced hseq store for previous step (off critical path) ----
    if (writeSeq && s > 0 && tid < 256) {
      int row = tid >> 4, idx = tid & 15;
      int col = nh * 128 + idx * 8;
      int c8 = col >> 3;
      u32x4 hval = *(const u32x4*)&h_lds[p][row * 256 + ((c8 ^ row) & 31) * 8];
      int tprev = dir ? (T_ - s) : (s - 1);
      *(u32x4*)&g_hseq[((size_t)tprev * B_ + rowb + row) * 512 + dir * 256 + col] = hval;
    }

    // ---- A-fragments from LDS buf[p] ----
    s8v af[8];
#pragma unroll
    for (int kt = 0; kt < 8; ++kt) {
      int c8 = kt * 4 + lq;
      af[kt] = *(const s8v*)&h_lds[p][l15 * 256 + ((c8 ^ l15) & 31) * 8];
    }
    // ---- MFMA ----
    f32x4 acc[4];
    const f32x4 zero4 = {0.f, 0.f, 0.f, 0.f};
#pragma unroll
    for (int g = 0; g < 4; ++g) acc[g] = zero4;
#pragma unroll
    for (int kt = 0; kt < 8; ++kt) {
#pragma unroll
      for (int g = 0; g < 4; ++g)
        acc[g] = __builtin_amdgcn_mfma_f32_16x16x32_bf16(af[kt], bfr[g][kt], acc[g], 0, 0, 0);
    }
    // ---- activations (rows lq*4+j, col mycol) ----
    float hf[4];
    ush hv[4];
#pragma unroll
    for (int j = 0; j < 4; ++j) {
      float vi = acc[0][j] + b2f(xv[j][0]) + bias_r[0];
      float vf = acc[1][j] + b2f(xv[j][1]) + bias_r[1];
      float vg = acc[2][j] + b2f(xv[j][2]) + bias_r[2];
      float vo = acc[3][j] + b2f(xv[j][3]) + bias_r[3];
      float ig = sigm(vi), fg = sigm(vf), gg = tanh_(vg), og = sigm(vo);
      float cc = fg * c_[j] + ig * gg;
      c_[j] = cc;
      hf[j] = og * tanh_(cc);
      hv[j] = f2b(hf[j]);
    }
    // ---- export own tile: 2 fused data+seq b64 atomics (critical path!) ----
    {
      ull seqw = ((ull)(sbase + (unsigned)s + 1u)) << 32;
      ull e0 = (ull)hv[0] | ((ull)hv[1] << 16) | seqw;
      ull e1 = (ull)hv[2] | ((ull)hv[3] << 16) | seqw;
      ull* ep = hxp + ((size_t)(p ^ 1) * 256 + mycol) * 8 + lq * 2;
      __hip_atomic_store(ep, e0, __ATOMIC_RELAXED, __HIP_MEMORY_SCOPE_SYSTEM);
      __hip_atomic_store(ep + 1, e1, __ATOMIC_RELAXED, __HIP_MEMORY_SCOPE_SYSTEM);
    }
    // ---- own h -> LDS buf[p^1] ----
    {
      int c8o = mycol >> 3, wo = mycol & 7;
#pragma unroll
      for (int j = 0; j < 4; ++j) {
        int row = lq * 4 + j;
        h_lds[p ^ 1][row * 256 + (((c8o ^ row) & 31) * 8 + wo)] = hv[j];
      }
    }
    // ---- prefetch xw for s+1 (hidden under next exchange) ----
    if (s + 1 < T_) {
      int tn = dir ? (T_ - 2 - s) : (s + 1);
      const ush* xp = g_xw + (((size_t)tn * 2 + dir) * B_ + rowb) * 1024 + mycol * 4;
#pragma unroll
      for (int j = 0; j < 4; ++j)
        xv[j] = *(const u16x4*)(xp + (size_t)(lq * 4 + j) * 1024);
    }
    // ---- final h (layer 2) kept via tail below ----
  }

  // ---- tail: import partner's last export, then write hseq tail / hT ----
  {
    const ull* a0 = hxp + ((size_t)(T_ & 1) * 256 + colp) * 8 + q * 2;
    unsigned target = sbase + (unsigned)T_;
    ull v0, v1;
    for (;;) {
      v0 = __hip_atomic_load(a0, __ATOMIC_RELAXED, __HIP_MEMORY_SCOPE_SYSTEM);
      v1 = __hip_atomic_load(a0 + 1, __ATOMIC_RELAXED, __HIP_MEMORY_SCOPE_SYSTEM);
      if ((unsigned)(v0 >> 32) >= target && (unsigned)(v1 >> 32) >= target) break;
      __builtin_amdgcn_s_sleep(1);
    }
    ush* dstl = &h_lds[T_ & 1][0];
    dstl[(q * 4 + 0) * 256 + (((c8p ^ (q * 4 + 0)) & 31) * 8 + wp)] = (ush)v0;
    dstl[(q * 4 + 1) * 256 + (((c8p ^ (q * 4 + 1)) & 31) * 8 + wp)] = (ush)(v0 >> 16);
    dstl[(q * 4 + 2) * 256 + (((c8p ^ (q * 4 + 2)) & 31) * 8 + wp)] = (ush)v1;
    dstl[(q * 4 + 3) * 256 + (((c8p ^ (q * 4 + 3)) & 31) * 8 + wp)] = (ush)(v1 >> 16);
  }
  __syncthreads();
  if (tid < 256) {
    int row = tid >> 4, idx = tid & 15;
    int col = nh * 128 + idx * 8;
    int c8 = col >> 3;
    u32x4 hval = *(const u32x4*)&h_lds[T_ & 1][row * 256 + ((c8 ^ row) & 31) * 8];
    if (writeSeq) {
      int tprev = dir ? 0 : (T_ - 1);
      *(u32x4*)&g_hseq[((size_t)tprev * B_ + rowb + row) * 512 + dir * 256 + col] = hval;
    } else {
      const ush* hp = (const ush*)&hval;
      float* dstf = g_hT + (size_t)(rowb + row) * 512 + dir * 256 + col;
      f32x4 f0, f1;
#pragma unroll
      for (int j = 0; j < 4; ++j) { f0[j] = b2f(hp[j]); f1[j] = b2f(hp[4 + j]); }
      *(f32x4*)dstf = f0;
      *(f32x4*)(dstf + 4) = f1;
    }
  }
}

// ============================================================
// Dense [128,512]@[512,10] + bias + softmax -> out f32
// ============================================================
__global__ __launch_bounds__(512, 1) void dense_softmax(
    const float* __restrict__ Wd, const float* __restrict__ bd, float* __restrict__ out)
{
  __shared__ float wT[10 * 512];
  __shared__ float part[512 * 10];
  int tid = threadIdx.x;
  for (int i = tid; i < 5120; i += 512) {
    int k = i / 10, j = i - k * 10;
    wT[j * 512 + k] = Wd[i];
  }
  __syncthreads();
  int row = tid >> 2, q = tid & 3;
  float acc[10];
#pragma unroll
  for (int j = 0; j < 10; ++j) acc[j] = 0.f;
  const float* hrow = g_hT + (size_t)row * 512 + q * 128;
  for (int kk = 0; kk < 32; ++kk) {
    f32x4 h4 = *(const f32x4*)(hrow + kk * 4);
#pragma unroll
    for (int j = 0; j < 10; ++j) {
      f32x4 w4 = *(const f32x4*)&wT[j * 512 + q * 128 + kk * 4];
      acc[j] += h4[0] * w4[0] + h4[1] * w4[1] + h4[2] * w4[2] + h4[3] * w4[3];
    }
  }
#pragma unroll
  for (int j = 0; j < 10; ++j) part[tid * 10 + j] = acc[j];
  __syncthreads();
  if (tid < 128) {
    float lg[10];
#pragma unroll
    for (int j = 0; j < 10; ++j)
      lg[j] = bd[j] + part[(tid * 4 + 0) * 10 + j] + part[(tid * 4 + 1) * 10 + j]
                    + part[(tid * 4 + 2) * 10 + j] + part[(tid * 4 + 3) * 10 + j];
    float m = lg[0];
#pragma unroll
    for (int j = 1; j < 10; ++j) m = fmaxf(m, lg[j]);
    float ssum = 0.f;
#pragma unroll
    for (int j = 0; j < 10; ++j) { lg[j] = __expf(lg[j] - m); ssum += lg[j]; }
    float inv = 1.f / ssum;
#pragma unroll
    for (int j = 0; j < 10; ++j) out[tid * 10 + j] = lg[j] * inv;
  }
}

extern "C" void kernel_launch(void* const* d_in, const int* in_sizes, int n_in,
                              void* d_out, int out_size, void* d_ws, size_t ws_size,
                              hipStream_t stream) {
  (void)in_sizes; (void)n_in; (void)d_ws; (void)ws_size; (void)out_size;
  const int* x = (const int*)d_in[0];
  const float* emb = (const float*)d_in[1];
  const float* W1f = (const float*)d_in[2];
  const float* U1f = (const float*)d_in[3];
  const float* b1f = (const float*)d_in[4];
  const float* W1b = (const float*)d_in[5];
  const float* U1b = (const float*)d_in[6];
  const float* b1b = (const float*)d_in[7];
  const float* W2f = (const float*)d_in[8];
  const float* U2f = (const float*)d_in[9];
  const float* b2f = (const float*)d_in[10];
  const float* W2b = (const float*)d_in[11];
  const float* U2b = (const float*)d_in[12];
  const float* b2b = (const float*)d_in[13];
  const float* Wd  = (const float*)d_in[14];
  const float* bd  = (const float*)d_in[15];
  float* out = (float*)d_out;

  void* hx_p = nullptr; void* wt_p = nullptr;
  hipGetSymbolAddress(&hx_p, HIP_SYMBOL(g_hx2));
  hipGetSymbolAddress(&wt_p, HIP_SYMBOL(g_wtall));
  ush* wt = (ush*)wt_p;
  // exchange seqs must be < first target every launch (graph replays!)
  hipMemsetAsync(hx_p, 0, sizeof(ull) * 8 * 2 * 2 * 256 * 8, stream);

  ush* wt1f = wt;                 ush* wt1b = wt1f + 131072;   // K=128
  ush* ut1f = wt1b + 131072;      ush* ut1b = ut1f + 262144;   // K=256
  ush* wt2f = ut1b + 262144;      ush* wt2b = wt2f + 524288;   // K=512
  ush* ut2f = wt2b + 524288;      ush* ut2b = ut2f + 262144;   // K=256

  prep_w<<<dim3(32, 1, 2), 256, 0, stream>>>(W1f, W1b, wt1f, wt1b, 128);
  prep_w<<<dim3(64, 1, 2), 256, 0, stream>>>(U1f, U1b, ut1f, ut1b, 256);
  prep_w<<<dim3(128, 1, 2), 256, 0, stream>>>(W2f, W2b, wt2f, wt2b, 512);
  prep_w<<<dim3(64, 1, 2), 256, 0, stream>>>(U2f, U2b, ut2f, ut2b, 256);

  // layer 1 input projection
  gemm_xw<<<dim3(8, T_, 2), 512, 0, stream>>>(0, x, emb, wt1f, wt1b, 128);
  // layer 1 recurrence (writes hseq)
  lstm_rec<<<32, 512, 0, stream>>>(0, ut1f, ut1b, b1f, b1b, 1);
  // layer 2 input projection
  gemm_xw<<<dim3(8, T_, 2), 512, 0, stream>>>(1, nullptr, nullptr, wt2f, wt2b, 512);
  // layer 2 recurrence (writes hT)
  lstm_rec<<<32, 512, 0, stream>>>(1, ut2f, ut2b, b2f, b2b, 0);
  // dense + softmax
  dense_softmax<<<1, 512, 0, stream>>>(Wd, bd, out);
}

// Round 4
// 3788.088 us; speedup vs baseline: 2.3633x; 1.0221x over previous
//
#include <hip/hip_runtime.h>
#include <hip/hip_bf16.h>

#define B_ 128
#define T_ 512
#define H_ 256
#define G4_ 1024   // 4*H
#define D_ 128

typedef short s8v   __attribute__((ext_vector_type(8)));   // 8 bf16 (as shorts) = MFMA A/B frag
typedef float f32x4 __attribute__((ext_vector_type(4)));
typedef unsigned short u16x4 __attribute__((ext_vector_type(4)));
typedef unsigned short u16x8 __attribute__((ext_vector_type(8)));
typedef unsigned int   u32x4 __attribute__((ext_vector_type(4)));
typedef unsigned short ush;
typedef unsigned long long ull;

// ---- static device workspace ----
// xw permuted: [t][dir][b][hc*4+g]  (4 gates contiguous per h-col). Reused by both layers:
// layer-2 gemm blocks overwrite [t] only after all layer-1 consumers of [t] are done.
__device__ __align__(256) ush   g_xw[(size_t)T_ * 2 * B_ * G4_];
__device__ __align__(256) ush   g_hseq[(size_t)T_ * B_ * 512];  // [t][b][dir*256+hc] bf16 (sc1-written)
// exchange: [slice16][dir2][ping2][col256][m4] b64 = {h[2m] bf16, h[2m+1] bf16, u32 seq}
__device__ __align__(256) ull   g_hx2[16 * 2 * 2 * 256 * 4];
__device__ __align__(256) float g_hT[B_ * 512];                 // final layer2 states, f32
__device__ __align__(256) unsigned g_tcnt[512];                 // hseq[t] readiness counters (target 64)
// pre-converted transposed bf16 weights: W1(2x131072) U1(2x262144) W2(2x524288) U2(2x262144)
__device__ __align__(256) ush   g_wtall[2359296];

__device__ __forceinline__ ush f2b(float f) {
  unsigned u = __builtin_bit_cast(unsigned, f);
  u += 0x7FFFu + ((u >> 16) & 1u);               // RNE
  return (ush)(u >> 16);
}
__device__ __forceinline__ float b2f(ush h) {
  unsigned u = ((unsigned)h) << 16;
  return __builtin_bit_cast(float, u);
}
__device__ __forceinline__ float sigm(float x) {
  x = fminf(15.f, fmaxf(-15.f, x));
  return 1.f / (1.f + __expf(-x));
}
__device__ __forceinline__ float tanh_(float x) {
  x = fminf(8.f, fmaxf(-8.f, x));
  float e = __expf(-2.f * x);
  return (1.f - e) / (1.f + e);
}

// ============================================================
// prep_w: W[k][n=1024] f32 -> WT[n][k] bf16, 64x64 LDS tile transpose.
// ============================================================
__global__ __launch_bounds__(256, 4) void prep_w(
    const float* __restrict__ Wf, const float* __restrict__ Wb,
    ush* __restrict__ WTf, ush* __restrict__ WTb, int K)
{
  __shared__ ush tile[64][65];
  const float* W = blockIdx.z ? Wb : Wf;
  ush* WT = blockIdx.z ? WTb : WTf;
  int nt = blockIdx.x & 15, kt = blockIdx.x >> 4;
  int tid = threadIdx.x;
  for (int i = tid; i < 4096; i += 256) {
    int k = i >> 6, n = i & 63;
    tile[k][n] = f2b(W[(size_t)(kt * 64 + k) * 1024 + nt * 64 + n]);
  }
  __syncthreads();
  for (int i = tid; i < 4096; i += 256) {
    int n = i >> 6, k = i & 63;
    WT[(size_t)(nt * 64 + n) * K + kt * 64 + k] = tile[k][n];
  }
}

// ============================================================
// gemm_xw: layer-1 input projection only (mode-0: A row = emb[x[b][t]], K=128).
// xw_p[t][dir][b][hc*4+g] = emb[x] @ W1[:,gate*256+hc]
// ============================================================
__global__ __launch_bounds__(512, 4) void gemm_xw(
    const int* __restrict__ xi, const float* __restrict__ emb,
    const ush* __restrict__ WTf, const ush* __restrict__ WTb)
{
  __shared__ __align__(16) ush A_lds[128 * 72];
  __shared__ __align__(16) ush BT_lds[128 * 72];
  const int tid = threadIdx.x;
  const int lane = tid & 63;
  const int w = tid >> 6;
  const int nb = blockIdx.x;
  const int t = blockIdx.y;
  const int dir = blockIdx.z;
  const ush* WT = dir ? WTb : WTf;

  const f32x4 zero4 = {0.f, 0.f, 0.f, 0.f};
  f32x4 acc[8];
#pragma unroll
  for (int i = 0; i < 8; ++i) acc[i] = zero4;

  const int rowA0 = tid >> 3;
  const int ccA = tid & 7;
  int idx0 = xi[rowA0 * T_ + t];
  int idx1 = xi[(rowA0 + 64) * T_ + t];

  for (int kc = 0; kc < 2; ++kc) {
    __syncthreads();
    {
      const float* s = emb + (size_t)idx0 * D_ + kc * 64 + ccA * 8;
      f32x4 a = *(const f32x4*)s;
      f32x4 b = *(const f32x4*)(s + 4);
      u16x8 v;
      v[0]=f2b(a[0]); v[1]=f2b(a[1]); v[2]=f2b(a[2]); v[3]=f2b(a[3]);
      v[4]=f2b(b[0]); v[5]=f2b(b[1]); v[6]=f2b(b[2]); v[7]=f2b(b[3]);
      *(u16x8*)&A_lds[rowA0 * 72 + ccA * 8] = v;
    }
    {
      const float* s = emb + (size_t)idx1 * D_ + kc * 64 + ccA * 8;
      f32x4 a = *(const f32x4*)s;
      f32x4 b = *(const f32x4*)(s + 4);
      u16x8 v;
      v[0]=f2b(a[0]); v[1]=f2b(a[1]); v[2]=f2b(a[2]); v[3]=f2b(a[3]);
      v[4]=f2b(b[0]); v[5]=f2b(b[1]); v[6]=f2b(b[2]); v[7]=f2b(b[3]);
      *(u16x8*)&A_lds[(rowA0 + 64) * 72 + ccA * 8] = v;
    }
    {
      int n = tid >> 2, k8 = (tid & 3) * 2;
      const ush* src = WT + (size_t)(nb * 128 + n) * 128 + kc * 64 + k8 * 8;
      *(u32x4*)&BT_lds[n * 72 + k8 * 8] = *(const u32x4*)src;
      *(u32x4*)&BT_lds[n * 72 + k8 * 8 + 8] = *(const u32x4*)(src + 8);
    }
    __syncthreads();
#pragma unroll
    for (int kt = 0; kt < 2; ++kt) {
      const int koff = kt * 32 + ((lane >> 4) << 3);
      s8v af = *(const s8v*)&A_lds[(w * 16 + (lane & 15)) * 72 + koff];
#pragma unroll
      for (int nt = 0; nt < 8; ++nt) {
        s8v bf = *(const s8v*)&BT_lds[(nt * 16 + (lane & 15)) * 72 + koff];
        acc[nt] = __builtin_amdgcn_mfma_f32_16x16x32_bf16(af, bf, acc[nt], 0, 0, 0);
      }
    }
  }
  ush* dst = g_xw + ((size_t)t * 2 + dir) * ((size_t)B_ * G4_);
#pragma unroll
  for (int nt = 0; nt < 8; ++nt) {
    int colg = nb * 128 + nt * 16 + (lane & 15);
    int g = colg >> 8, hc = colg & 255;
#pragma unroll
    for (int jj = 0; jj < 4; ++jj) {
      int row = w * 16 + ((lane >> 4) << 2) + jj;
      dst[(size_t)row * 1024 + hc * 4 + g] = f2b(acc[nt][jj]);
    }
  }
}

// ============================================================
// mega: blocks [0,64): persistent LSTM recurrence (M=8 batch rows per WG).
//   bx: slice = bx&15 (8 rows), dir = (bx>>4)&1, nh = bx>>5 (128-col half). Pair = bx^32.
//   Exchange granule: b64 {h[2m], h[2m+1], seq}; 2 stores per producing lane (lq<2),
//   1 load per consumer thread. xw prefetch issued at top of step (1 full step of aging
//   before the next poll's vmcnt(0) drain).
// blocks [64, 64+ngemm): persistent layer-2 input GEMM, consuming hseq[t] as soon as
//   g_tcnt[t]==64, in readiness order t = 255,256,254,257,...; writes xw2 in place.
// ============================================================
__global__ __launch_bounds__(512, 2) void mega(
    int layer, const ush* __restrict__ UTf, const ush* __restrict__ UTb,
    const float* __restrict__ bfp, const float* __restrict__ bbp,
    int writeSeq, int ngemm,
    const ush* __restrict__ WT2f, const ush* __restrict__ WT2b)
{
  __shared__ __align__(16) ush smem[2 * 128 * 72];   // 36 KB union
  const int bx = blockIdx.x;
  const int tid = threadIdx.x;
  const int lane = tid & 63;
  const int w = tid >> 6;
  const int l15 = lane & 15;
  const int lq = lane >> 4;

  if (bx < 64) {
    // ================= LSTM role =================
    const int slice = bx & 15;
    const int dir = (bx >> 4) & 1;
    const int nh = bx >> 5;
    const ush* UT = dir ? UTb : UTf;
    const float* bias = dir ? bbp : bfp;
    const int mycol = nh * 128 + w * 16 + l15;
    const int rowb = slice * 8;
    const unsigned sbase = (unsigned)(layer * T_);
    ush* h0 = smem;   // [2][16*256] ping-pong, XOR-swizzled; rows 8..15 stay zero

    // hoist U-half B-fragments (128 VGPRs/wave)
    s8v bfr[4][8];
#pragma unroll
    for (int g = 0; g < 4; ++g) {
      const ush* up = UT + (size_t)(g * 256 + mycol) * 256;
#pragma unroll
      for (int kt = 0; kt < 8; ++kt)
        bfr[g][kt] = *(const s8v*)(up + kt * 32 + lq * 8);
    }
    float bias_r[4];
#pragma unroll
    for (int g = 0; g < 4; ++g) bias_r[g] = bias[g * 256 + mycol];

    // zero both h buffers (16 KB)
    {
      ull* z = (ull*)smem;
      z[tid] = 0ull; z[tid + 512] = 0ull; z[tid + 1024] = 0ull; z[tid + 1536] = 0ull;
    }
    __syncthreads();

    float c_[4] = {0.f, 0.f, 0.f, 0.f};
    ull* hx_base = g_hx2 + (size_t)(slice * 2 + dir) * 2048;
    const int colp = (nh ^ 1) * 128 + (tid >> 2);
    const int m_ = tid & 3;
    const int c8p = colp >> 3, wp = colp & 7;
    const int xrow = (lq & 1) * 4;   // M=8: lanes lq>=2 duplicate rows 0..7 (clamped)

    u16x4 xv[4];
    {
      int t0 = dir ? (T_ - 1) : 0;
      const ush* xp = g_xw + (((size_t)t0 * 2 + dir) * B_ + rowb) * 1024 + mycol * 4;
#pragma unroll
      for (int j = 0; j < 4; ++j) xv[j] = *(const u16x4*)(xp + (size_t)(xrow + j) * 1024);
    }

    for (int s = 0; s < T_; ++s) {
      const int p = s & 1;
      // ---- import partner half (poll drains vm ops aged ~1 step) ----
      if (s > 0) {
        ull* aP = hx_base + ((size_t)p * 256 + colp) * 4 + m_;
        unsigned target = sbase + (unsigned)s;
        ull v;
        for (;;) {
          v = __hip_atomic_load(aP, __ATOMIC_RELAXED, __HIP_MEMORY_SCOPE_SYSTEM);
          if ((unsigned)(v >> 32) >= target) break;
          __builtin_amdgcn_s_sleep(1);
        }
        int r0 = 2 * m_;
        ush* dl = h0 + p * 4096;
        dl[r0 * 256 + (((c8p ^ r0) & 31) * 8 + wp)] = (ush)v;
        dl[(r0 + 1) * 256 + (((c8p ^ (r0 + 1)) & 31) * 8 + wp)] = (ush)(v >> 16);
      }
      __syncthreads();
      // ---- readiness counter for t(s-2): its sc1 hseq stores were drained by this poll ----
      if (writeSeq) {
        if (tid == 0 && s >= 2) {
          int td = dir ? (T_ + 1 - s) : (s - 2);
          __hip_atomic_fetch_add(&g_tcnt[td], 1u, __ATOMIC_RELAXED, __HIP_MEMORY_SCOPE_SYSTEM);
        }
        // ---- hseq store for t(s-1), sc1 b64s (coalesced 16B/thread) ----
        if (s > 0 && tid < 128) {
          int row8 = tid >> 4, idx = tid & 15;
          int col = nh * 128 + idx * 8;
          int c8 = col >> 3;
          const ush* srcl = h0 + p * 4096 + row8 * 256 + ((c8 ^ row8) & 31) * 8;
          ull lo = *(const ull*)srcl;
          ull hi = *(const ull*)(srcl + 4);
          int tprev = dir ? (T_ - s) : (s - 1);
          ull* dst = (ull*)&g_hseq[((size_t)tprev * B_ + rowb + row8) * 512 + dir * 256 + col];
          __hip_atomic_store(dst, lo, __ATOMIC_RELAXED, __HIP_MEMORY_SCOPE_SYSTEM);
          __hip_atomic_store(dst + 1, hi, __ATOMIC_RELAXED, __HIP_MEMORY_SCOPE_SYSTEM);
        }
      }
      // ---- xw prefetch for s+1 (ages a full step before next poll's drain) ----
      u16x4 xn[4];
      if (s + 1 < T_) {
        int tn = dir ? (T_ - 2 - s) : (s + 1);
        const ush* xp = g_xw + (((size_t)tn * 2 + dir) * B_ + rowb) * 1024 + mycol * 4;
#pragma unroll
        for (int j = 0; j < 4; ++j) xn[j] = *(const u16x4*)(xp + (size_t)(xrow + j) * 1024);
      }
      // ---- MFMA: z[16,64] per wave (rows 8..15 are zero) ----
      s8v af[8];
#pragma unroll
      for (int kt = 0; kt < 8; ++kt) {
        int c8 = kt * 4 + lq;
        af[kt] = *(const s8v*)(h0 + p * 4096 + l15 * 256 + ((c8 ^ l15) & 31) * 8);
      }
      f32x4 acc[4];
      const f32x4 zero4 = {0.f, 0.f, 0.f, 0.f};
#pragma unroll
      for (int g = 0; g < 4; ++g) acc[g] = zero4;
#pragma unroll
      for (int kt = 0; kt < 8; ++kt) {
#pragma unroll
        for (int g = 0; g < 4; ++g)
          acc[g] = __builtin_amdgcn_mfma_f32_16x16x32_bf16(af[kt], bfr[g][kt], acc[g], 0, 0, 0);
      }
      // ---- activations ----
      float hf[4];
      ush hv[4];
#pragma unroll
      for (int j = 0; j < 4; ++j) {
        float vi = acc[0][j] + b2f(xv[j][0]) + bias_r[0];
        float vf = acc[1][j] + b2f(xv[j][1]) + bias_r[1];
        float vg = acc[2][j] + b2f(xv[j][2]) + bias_r[2];
        float vo = acc[3][j] + b2f(xv[j][3]) + bias_r[3];
        float ig = sigm(vi), fg = sigm(vf), gg = tanh_(vg), og = sigm(vo);
        float cc = fg * c_[j] + ig * gg;
        c_[j] = cc;
        hf[j] = og * tanh_(cc);
        hv[j] = f2b(hf[j]);
      }
      (void)hf;
      // ---- export + own-h LDS (only lanes owning valid rows 0..7) ----
      if (lq < 2) {
        ull seqw = ((ull)(sbase + (unsigned)s + 1u)) << 32;
        ull e0 = (ull)hv[0] | ((ull)hv[1] << 16) | seqw;
        ull e1 = (ull)hv[2] | ((ull)hv[3] << 16) | seqw;
        ull* ep = hx_base + ((size_t)(p ^ 1) * 256 + mycol) * 4 + 2 * lq;
        __hip_atomic_store(ep, e0, __ATOMIC_RELAXED, __HIP_MEMORY_SCOPE_SYSTEM);
        __hip_atomic_store(ep + 1, e1, __ATOMIC_RELAXED, __HIP_MEMORY_SCOPE_SYSTEM);
        int c8o = mycol >> 3, wo = mycol & 7;
        ush* dl = h0 + (p ^ 1) * 4096;
#pragma unroll
        for (int j = 0; j < 4; ++j) {
          int r = lq * 4 + j;
          dl[r * 256 + (((c8o ^ r) & 31) * 8 + wo)] = hv[j];
        }
      }
#pragma unroll
      for (int j = 0; j < 4; ++j) xv[j] = xn[j];
    }
    // ---- tail: final-step data is in buf[T&1] (own cols) ----
    __syncthreads();
    const ush* bufl = h0 + (T_ & 1) * 4096;
    if (writeSeq) {
      if (tid < 128) {
        int row8 = tid >> 4, idx = tid & 15;
        int col = nh * 128 + idx * 8;
        int c8 = col >> 3;
        const ush* srcl = bufl + row8 * 256 + ((c8 ^ row8) & 31) * 8;
        ull lo = *(const ull*)srcl;
        ull hi = *(const ull*)(srcl + 4);
        int tlast = dir ? 0 : (T_ - 1);
        ull* dst = (ull*)&g_hseq[((size_t)tlast * B_ + rowb + row8) * 512 + dir * 256 + col];
        __hip_atomic_store(dst, lo, __ATOMIC_RELAXED, __HIP_MEMORY_SCOPE_SYSTEM);
        __hip_atomic_store(dst + 1, hi, __ATOMIC_RELAXED, __HIP_MEMORY_SCOPE_SYSTEM);
      }
      asm volatile("s_waitcnt vmcnt(0)" ::: "memory");
      __syncthreads();
      if (tid == 0) {
        int ta = dir ? 1 : (T_ - 2);
        int tb2 = dir ? 0 : (T_ - 1);
        __hip_atomic_fetch_add(&g_tcnt[ta], 1u, __ATOMIC_RELAXED, __HIP_MEMORY_SCOPE_SYSTEM);
        __hip_atomic_fetch_add(&g_tcnt[tb2], 1u, __ATOMIC_RELAXED, __HIP_MEMORY_SCOPE_SYSTEM);
      }
    } else {
      if (tid < 128) {
        int row8 = tid >> 4, idx = tid & 15;
        int col = nh * 128 + idx * 8;
        int c8 = col >> 3;
        const ush* srcl = bufl + row8 * 256 + ((c8 ^ row8) & 31) * 8;
        float* dstf = g_hT + (size_t)(rowb + row8) * 512 + dir * 256 + col;
        f32x4 f0, f1;
#pragma unroll
        for (int j = 0; j < 4; ++j) { f0[j] = b2f(srcl[j]); f1[j] = b2f(srcl[4 + j]); }
        *(f32x4*)dstf = f0;
        *(f32x4*)(dstf + 4) = f1;
      }
    }
  } else {
    // ================= layer-2 GEMM role =================
    if (ngemm <= 0) return;
    ush* A_lds = smem;              // [128][72]
    ush* BT_lds = smem + 128 * 72;  // [128][72]
    const int wg = bx - 64;
    const int rowA0 = tid >> 3;
    const int ccA = tid & 7;

    for (int u = wg; u < 8192; u += ngemm) {
      int pairIdx = u >> 4, sub = u & 15;
      int nb = sub & 7, gdir = sub >> 3;
      int t = (pairIdx & 1) ? (255 - (pairIdx >> 1)) : (256 + (pairIdx >> 1));
      const ush* WT = gdir ? WT2b : WT2f;
      // readiness poll: all 64 lstm WGs have certified hseq[t]
      for (;;) {
        unsigned v = __hip_atomic_load(&g_tcnt[t], __ATOMIC_RELAXED, __HIP_MEMORY_SCOPE_SYSTEM);
        if (v >= 64u) break;
        __builtin_amdgcn_s_sleep(4);
      }
      const f32x4 zero4 = {0.f, 0.f, 0.f, 0.f};
      f32x4 acc[8];
#pragma unroll
      for (int i = 0; i < 8; ++i) acc[i] = zero4;
      for (int kc = 0; kc < 8; ++kc) {
        __syncthreads();   // also guards LDS reuse across units
        {
          const ush* s0 = g_hseq + ((size_t)(t * B_ + rowA0)) * 512 + kc * 64 + ccA * 8;
          *(u32x4*)&A_lds[rowA0 * 72 + ccA * 8] = *(const u32x4*)s0;
          const ush* s1 = g_hseq + ((size_t)(t * B_ + rowA0 + 64)) * 512 + kc * 64 + ccA * 8;
          *(u32x4*)&A_lds[(rowA0 + 64) * 72 + ccA * 8] = *(const u32x4*)s1;
        }
        {
          int n = tid >> 2, k8 = (tid & 3) * 2;
          const ush* src = WT + (size_t)(nb * 128 + n) * 512 + kc * 64 + k8 * 8;
          *(u32x4*)&BT_lds[n * 72 + k8 * 8] = *(const u32x4*)src;
          *(u32x4*)&BT_lds[n * 72 + k8 * 8 + 8] = *(const u32x4*)(src + 8);
        }
        __syncthreads();
#pragma unroll
        for (int kt = 0; kt < 2; ++kt) {
          const int koff = kt * 32 + (lq << 3);
          s8v af = *(const s8v*)&A_lds[(w * 16 + l15) * 72 + koff];
#pragma unroll
          for (int nt = 0; nt < 8; ++nt) {
            s8v bf = *(const s8v*)&BT_lds[(nt * 16 + l15) * 72 + koff];
            acc[nt] = __builtin_amdgcn_mfma_f32_16x16x32_bf16(af, bf, acc[nt], 0, 0, 0);
          }
        }
      }
      ush* dst = g_xw + ((size_t)t * 2 + gdir) * ((size_t)B_ * G4_);
#pragma unroll
      for (int nt = 0; nt < 8; ++nt) {
        int colg = nb * 128 + nt * 16 + l15;
        int g = colg >> 8, hc = colg & 255;
#pragma unroll
        for (int jj = 0; jj < 4; ++jj) {
          int row = w * 16 + (lq << 2) + jj;
          dst[(size_t)row * 1024 + hc * 4 + g] = f2b(acc[nt][jj]);
        }
      }
    }
  }
}

// ============================================================
// Dense [128,512]@[512,10] + bias + softmax -> out f32
// ============================================================
__global__ __launch_bounds__(512, 1) void dense_softmax(
    const float* __restrict__ Wd, const float* __restrict__ bd, float* __restrict__ out)
{
  __shared__ float wT[10 * 512];
  __shared__ float part[512 * 10];
  int tid = threadIdx.x;
  for (int i = tid; i < 5120; i += 512) {
    int k = i / 10, j = i - k * 10;
    wT[j * 512 + k] = Wd[i];
  }
  __syncthreads();
  int row = tid >> 2, q = tid & 3;
  float acc[10];
#pragma unroll
  for (int j = 0; j < 10; ++j) acc[j] = 0.f;
  const float* hrow = g_hT + (size_t)row * 512 + q * 128;
  for (int kk = 0; kk < 32; ++kk) {
    f32x4 h4 = *(const f32x4*)(hrow + kk * 4);
#pragma unroll
    for (int j = 0; j < 10; ++j) {
      f32x4 w4 = *(const f32x4*)&wT[j * 512 + q * 128 + kk * 4];
      acc[j] += h4[0] * w4[0] + h4[1] * w4[1] + h4[2] * w4[2] + h4[3] * w4[3];
    }
  }
#pragma unroll
  for (int j = 0; j < 10; ++j) part[tid * 10 + j] = acc[j];
  __syncthreads();
  if (tid < 128) {
    float lg[10];
#pragma unroll
    for (int j = 0; j < 10; ++j)
      lg[j] = bd[j] + part[(tid * 4 + 0) * 10 + j] + part[(tid * 4 + 1) * 10 + j]
                    + part[(tid * 4 + 2) * 10 + j] + part[(tid * 4 + 3) * 10 + j];
    float m = lg[0];
#pragma unroll
    for (int j = 1; j < 10; ++j) m = fmaxf(m, lg[j]);
    float ssum = 0.f;
#pragma unroll
    for (int j = 0; j < 10; ++j) { lg[j] = __expf(lg[j] - m); ssum += lg[j]; }
    float inv = 1.f / ssum;
#pragma unroll
    for (int j = 0; j < 10; ++j) out[tid * 10 + j] = lg[j] * inv;
  }
}

extern "C" void kernel_launch(void* const* d_in, const int* in_sizes, int n_in,
                              void* d_out, int out_size, void* d_ws, size_t ws_size,
                              hipStream_t stream) {
  (void)in_sizes; (void)n_in; (void)d_ws; (void)ws_size; (void)out_size;
  const int* x = (const int*)d_in[0];
  const float* emb = (const float*)d_in[1];
  const float* W1f = (const float*)d_in[2];
  const float* U1f = (const float*)d_in[3];
  const float* b1f = (const float*)d_in[4];
  const float* W1b = (const float*)d_in[5];
  const float* U1b = (const float*)d_in[6];
  const float* b1b = (const float*)d_in[7];
  const float* W2f = (const float*)d_in[8];
  const float* U2f = (const float*)d_in[9];
  const float* b2f = (const float*)d_in[10];
  const float* W2b = (const float*)d_in[11];
  const float* U2b = (const float*)d_in[12];
  const float* b2b = (const float*)d_in[13];
  const float* Wd  = (const float*)d_in[14];
  const float* bd  = (const float*)d_in[15];
  float* out = (float*)d_out;

  void* hx_p = nullptr; void* wt_p = nullptr; void* tc_p = nullptr;
  hipGetSymbolAddress(&hx_p, HIP_SYMBOL(g_hx2));
  hipGetSymbolAddress(&wt_p, HIP_SYMBOL(g_wtall));
  hipGetSymbolAddress(&tc_p, HIP_SYMBOL(g_tcnt));
  ush* wt = (ush*)wt_p;
  // seq values and counters must start below first targets every launch (graph replays!)
  hipMemsetAsync(hx_p, 0, sizeof(ull) * 16 * 2 * 2 * 256 * 4, stream);
  hipMemsetAsync(tc_p, 0, sizeof(unsigned) * 512, stream);

  ush* wt1f = wt;                 ush* wt1b = wt1f + 131072;   // K=128
  ush* ut1f = wt1b + 131072;      ush* ut1b = ut1f + 262144;   // K=256
  ush* wt2f = ut1b + 262144;      ush* wt2b = wt2f + 524288;   // K=512
  ush* ut2f = wt2b + 524288;      ush* ut2b = ut2f + 262144;   // K=256

  prep_w<<<dim3(32, 1, 2), 256, 0, stream>>>(W1f, W1b, wt1f, wt1b, 128);
  prep_w<<<dim3(64, 1, 2), 256, 0, stream>>>(U1f, U1b, ut1f, ut1b, 256);
  prep_w<<<dim3(128, 1, 2), 256, 0, stream>>>(W2f, W2b, wt2f, wt2b, 512);
  prep_w<<<dim3(64, 1, 2), 256, 0, stream>>>(U2f, U2b, ut2f, ut2b, 256);

  // layer 1 input projection (emb gather, K=128)
  gemm_xw<<<dim3(8, T_, 2), 512, 0, stream>>>(x, emb, wt1f, wt1b);
  // layer 1 recurrence + fused layer-2 input projection (160 gemm WGs)
  mega<<<224, 512, 0, stream>>>(0, ut1f, ut1b, b1f, b1b, 1, 160, wt2f, wt2b);
  // layer 2 recurrence (lstm blocks only)
  mega<<<64, 512, 0, stream>>>(1, ut2f, ut2b, b2f, b2b, 0, 0, nullptr, nullptr);
  // dense + softmax
  dense_softmax<<<1, 512, 0, stream>>>(Wd, bd, out);
}